// Round 6
// baseline (645.260 us; speedup 1.0000x reference)
//
#include <hip/hip_runtime.h>
#include <hip/hip_bf16.h>

typedef __attribute__((ext_vector_type(8))) __bf16 bf16x8;
typedef __attribute__((ext_vector_type(4))) __bf16 bf16x4;
typedef __attribute__((ext_vector_type(4))) float f32x4;
typedef unsigned int u32;

#define TM 64          // rows per block (R4 lesson: do not shrink)
#define LDXM 40        // masked-x tile stride (elements)
#define LDH 136        // h tile stride (elements)
#define LDP 104        // params stride: 4 dims * 26 elems (R1-verbatim layout)
#define SPBYTES 13312  // one sp buffer: 64 rows * 104 * 2 B
#define MIN_BIN 1e-4f
#define MIN_SLOPE 1e-4f

// bf16 weight cache layout in d_ws (element offsets)
#define OW1 0
#define OW2 4096
#define OW3 20480
#define OW4 36864
#define NWELEM 139264   // total weight elements (W1+W2+W3+W4)

// ---- prep: fp32 weights -> bf16 cache in workspace (runs every launch) ----
__global__ void prep_weights(const float* __restrict__ W1, const float* __restrict__ W2,
                             const float* __restrict__ W3, const float* __restrict__ W4,
                             __hip_bfloat16* __restrict__ ws) {
    int e = (blockIdx.x * blockDim.x + threadIdx.x) * 4;
    if (e >= NWELEM) return;
    const float* src;
    if (e < OW2)      src = W1 + e;
    else if (e < OW3) src = W2 + (e - OW2);
    else if (e < OW4) src = W3 + (e - OW3);
    else              src = W4 + (e - OW4);
    f32x4 v = *(const f32x4*)src;
    bf16x4 o;
    o[0] = (__bf16)v[0]; o[1] = (__bf16)v[1]; o[2] = (__bf16)v[2]; o[3] = (__bf16)v[3];
    *(bf16x4*)&ws[e] = o;
}

// load 8 contiguous fp32, convert to bf16x8 (fallback path)
__device__ inline bf16x8 cvt8(const float* __restrict__ p) {
    f32x4 a = *(const f32x4*)p;
    f32x4 b = *(const f32x4*)(p + 4);
    bf16x8 r;
    r[0] = (__bf16)a[0]; r[1] = (__bf16)a[1]; r[2] = (__bf16)a[2]; r[3] = (__bf16)a[3];
    r[4] = (__bf16)b[0]; r[5] = (__bf16)b[1]; r[6] = (__bf16)b[2]; r[7] = (__bf16)b[3];
    return r;
}

template<bool USE_WS>
__device__ inline bf16x8 wfrag(const __hip_bfloat16* __restrict__ wsW,
                               const float* __restrict__ Wg, size_t off) {
    if constexpr (USE_WS) return *(const bf16x8*)(wsW + off);
    else                  return cvt8(Wg + off);
}

// ---- A-fragment hoist: wave w owns batch rows 16w..16w+15.  The MFMA
// h-fragment depends only on (m, q, kt) — NOT on the output tile — so load
// once per layer (4 x ds_read_b128 = 16 VGPRs) and reuse for ALL col tiles.
// This removes the dominant LDS traffic (L4 alone was 832 KB/block of
// re-reads; now 16 KB once per block).
template<int NKT>
__device__ inline void load_afrag(const __hip_bfloat16* hin, int ldin,
                                  int wave, int m, int q, bf16x8 (&af)[4]) {
#pragma unroll
    for (int kt = 0; kt < NKT; kt++)
        af[kt] = *(const bf16x8*)&hin[(wave * 16 + m) * ldin + kt * 32 + q * 8];
}

// ---- one dense layer: wave computes ALL 8 col-tiles for its 16 rows.
// SWAPPED operand order mfma(W-frag, h-frag): D row(q*4+r) = out col
// n0+q*4+r, D col(m) = batch row 16w+m -> bias preloads as f32x4, store is
// one packed ds_write_b64 per tile.
template<bool USE_WS, int K>
__device__ inline void dense_layer(const __hip_bfloat16* __restrict__ wsW,
                                   const float* __restrict__ Wg,
                                   const float* __restrict__ bg,
                                   const bf16x8 (&af)[4],
                                   __hip_bfloat16* hout,
                                   int wave, int m, int q)
{
#pragma unroll
    for (int nt = 0; nt < 8; nt++) {
        const int n0 = nt * 16;
        bf16x8 bfrag[K / 32];
#pragma unroll
        for (int kt = 0; kt < K / 32; kt++)
            bfrag[kt] = wfrag<USE_WS>(wsW, Wg, (size_t)(n0 + m) * K + kt * 32 + q * 8);
        f32x4 acc = *(const f32x4*)&bg[n0 + q * 4];
#pragma unroll
        for (int kt = 0; kt < K / 32; kt++)
            acc = __builtin_amdgcn_mfma_f32_16x16x32_bf16(bfrag[kt], af[kt], acc, 0, 0, 0);
        bf16x4 o;
#pragma unroll
        for (int r = 0; r < 4; r++)
            o[r] = (__bf16)fmaxf(acc[r], 0.f);
        *(bf16x4*)&hout[(wave * 16 + m) * LDH + n0 + q * 4] = o;
    }
}

// ---- layer-4 chunk: wave computes all 7 tiles (100+straddle cols) for its
// 16 rows, h3-frags from registers (ZERO LDS reads), result -> sp buffer.
// ORIGINAL operand order mfma(h-frag, W-frag): D row(q*4+r) = batch row
// 16w+q*4+r, D col(m) = W4 col -> writes match R1's sp layout.
template<bool USE_WS>
__device__ inline void gemm_chunk(const __hip_bfloat16* __restrict__ wsW4,
                                  const float* __restrict__ W4g,
                                  const float* __restrict__ b4g,
                                  const bf16x8 (&af)[4],
                                  __hip_bfloat16* spn,
                                  int c, int wave, int m, int q)
{
    const int t0 = (25 * c) >> 2;             // 0,6,12,18,25,31,37,43
#pragma unroll
    for (int tt = 0; tt < 7; tt++) {
        const int colg = (t0 + tt) * 16 + m;  // 0..799
        bf16x8 bfrag[4];
#pragma unroll
        for (int kt = 0; kt < 4; kt++)
            bfrag[kt] = wfrag<USE_WS>(wsW4, W4g, (size_t)colg * 128 + kt * 32 + q * 8);
        const float bias = b4g[colg];
        f32x4 a = {bias, bias, bias, bias};
#pragma unroll
        for (int kt = 0; kt < 4; kt++)
            a = __builtin_amdgcn_mfma_f32_16x16x32_bf16(af[kt], bfrag[kt], a, 0, 0, 0);
        const int lc = colg - 100 * c;        // col within chunk
        if (lc >= 0 && lc < 100) {
            const int dl = lc / 25;
            const int spcol = dl * 26 + (lc - dl * 25);
#pragma unroll
            for (int r = 0; r < 4; r++)
                spn[(wave * 16 + q * 4 + r) * LDP + spcol] = __float2bfloat16(a[r]);
        }
    }
}

template<bool USE_WS>
__global__ __launch_bounds__(256, 4)
void rqs_fused_kernel(const float* __restrict__ xg,
                      const float* __restrict__ W1g, const float* __restrict__ b1g,
                      const float* __restrict__ W2g, const float* __restrict__ b2g,
                      const float* __restrict__ W3g, const float* __restrict__ b3g,
                      const float* __restrict__ W4g, const float* __restrict__ b4g,
                      const __hip_bfloat16* __restrict__ ws,
                      float* __restrict__ outg, int nrows)
{
    // LDS 34 KB -> 4 blocks/CU.  After h3 is hoisted to registers, BOTH tile
    // regions are dead -> the sp double-buffer overlays them (1 barrier/chunk,
    // GEMM(c+1)->sp_next runs concurrently with spline(c)<-sp_cur).
    __shared__ __align__(16) unsigned char smem[17408 + 17408];
    __hip_bfloat16* const shA = (__hip_bfloat16*)smem;              // h1/h3 [64][136]
    __hip_bfloat16* const shB = (__hip_bfloat16*)(smem + 17408);    // h2 [64][136]
    __hip_bfloat16* const sx  = (__hip_bfloat16*)(smem + 17408);    // x_masked [64][40]
    __hip_bfloat16* const sp0 = (__hip_bfloat16*)smem;              // params buf 0
    __hip_bfloat16* const sp1 = (__hip_bfloat16*)(smem + SPBYTES);  // params buf 1

    const int tid  = threadIdx.x;
    const int wave = tid >> 6;                // 0..3
    const int lane = tid & 63;
    const int m    = lane & 15;
    const int q    = lane >> 4;
    const int row0 = blockIdx.x * TM;

    // ---- stage masked x (fp32->bf16) + exact fp32 passthrough y[:, :32] ----
    {
        const int r = tid >> 2, q8 = tid & 3;                 // 64 rows x 4 chunks of 8
        const float* src = &xg[(size_t)(row0 + r) * 64 + q8 * 8];
        f32x4 a = *(const f32x4*)src;
        f32x4 b = *(const f32x4*)(src + 4);
        float* dst = &outg[(size_t)(row0 + r) * 64 + q8 * 8];
        *(f32x4*)dst = a;
        *(f32x4*)(dst + 4) = b;
        bf16x8 v;
        v[0] = (__bf16)a[0]; v[1] = (__bf16)a[1]; v[2] = (__bf16)a[2]; v[3] = (__bf16)a[3];
        v[4] = (__bf16)b[0]; v[5] = (__bf16)b[1]; v[6] = (__bf16)b[2]; v[7] = (__bf16)b[3];
        *(bf16x8*)&sx[r * LDXM + q8 * 8] = v;
    }
    __syncthreads();

    // ---- MLP layers 1..3, A-frags hoisted to registers per layer ----
    bf16x8 af[4];
    load_afrag<1>(sx, LDXM, wave, m, q, af);
    dense_layer<USE_WS, 32>(ws + OW1, W1g, b1g, af, shA, wave, m, q);
    __syncthreads();
    load_afrag<4>(shA, LDH, wave, m, q, af);
    dense_layer<USE_WS, 128>(ws + OW2, W2g, b2g, af, shB, wave, m, q);
    __syncthreads();
    load_afrag<4>(shB, LDH, wave, m, q, af);
    dense_layer<USE_WS, 128>(ws + OW3, W3g, b3g, af, shA, wave, m, q);
    __syncthreads();
    load_afrag<4>(shA, LDH, wave, m, q, af);  // h3 -> 16 VGPRs, persists all chunks
    __syncthreads();                          // all waves done reading shA

    const int dim  = tid & 3;                 // spline: (row, 4-dim lane group)
    const int srow = tid >> 2;                // 0..63
    float ldacc = 0.f;

    // ---- pipelined layer 4 + spline, 8 chunks of 4 dims, sp double-buffer ----
    gemm_chunk<USE_WS>(ws + OW4, W4g, b4g, af, sp0, 0, wave, m, q);
    float xcur = xg[(size_t)(row0 + srow) * 64 + 32 + dim];
    __syncthreads();

    for (int c = 0; c < 8; c++) {
        // next chunk's x load a full phase ahead of use
        const int cn = (c < 7) ? c + 1 : 7;
        const float xnext = xg[(size_t)(row0 + srow) * 64 + 32 + cn * 4 + dim];

        // GEMM for chunk c+1 -> other sp buffer (af in regs: no LDS reads)
        if (c < 7)
            gemm_chunk<USE_WS>(ws + OW4, W4g, b4g, af,
                               (c & 1) ? sp0 : sp1, c + 1, wave, m, q);

        // ---- spline: one (row, dim) cell per thread, reads sp of chunk c ----
        {
            const __hip_bfloat16* spc = (c & 1) ? sp1 : sp0;
            const __hip_bfloat16* pr = &spc[srow * LDP + dim * 26];
            float raw[25];
            const u32* pu = (const u32*)pr;   // dword idx = 52*srow + 13*dim
#pragma unroll
            for (int j = 0; j < 12; j++) {
                u32 u = pu[j];
                raw[2 * j]     = __uint_as_float(u << 16);
                raw[2 * j + 1] = __uint_as_float(u & 0xffff0000u);
            }
            raw[24] = __bfloat162float(pr[24]);

            // softmax without max-subtraction: |raw| << 88, exp cannot overflow,
            // ratio is mathematically identical
            float ew[8], eh[8];
            float sumw = 0.f, sumh = 0.f;
#pragma unroll
            for (int j = 0; j < 8; j++) {
                ew[j] = __expf(raw[j]);      sumw += ew[j];
                eh[j] = __expf(raw[8 + j]);  sumh += eh[j];
            }
            const float scw = (10.f - 8.f * MIN_BIN) / sumw;
            const float sch = (10.f - 8.f * MIN_BIN) / sumh;

            const int gdim = c * 4 + dim;
            const float x = xcur;
            const bool inside = (x >= -5.f) && (x <= 5.f);
            const float xc = fminf(fmaxf(x, -5.f), 5.f);

            // sequential cumsum + bin select (matches jnp.cumsum order)
            float cx = -5.f, cy = -5.f;
            float xk = -5.f, yk = -5.f, wk = 0.f, hk = 0.f, r0 = 0.f, r1 = 0.f;
#pragma unroll
            for (int j = 0; j < 8; j++) {
                const float wj = fmaf(ew[j], scw, MIN_BIN);
                const float hj = fmaf(eh[j], sch, MIN_BIN);
                const bool sel = xc >= cx;
                xk = sel ? cx : xk;  yk = sel ? cy : yk;
                wk = sel ? wj : wk;  hk = sel ? hj : hk;
                r0 = sel ? raw[16 + j] : r0;
                r1 = sel ? raw[17 + j] : r1;
                cx += wj; cy += hj;
            }

            // softplus on the two selected slopes; __logf(1+t) replaces libm
            // log1pf (abs err ~6e-8, far below bf16 noise)
            const float dk  = MIN_SLOPE + fmaxf(r0, 0.f) + __logf(1.f + __expf(-fabsf(r0)));
            const float dk1 = MIN_SLOPE + fmaxf(r1, 0.f) + __logf(1.f + __expf(-fabsf(r1)));

            const float rw = 1.f / wk;
            const float xi = (xc - xk) * rw;
            const float om = 1.f - xi;
            const float sk = hk * rw;
            const float xo = xi * om;
            const float den = fmaf(dk1 + dk - 2.f * sk, xo, sk);
            const float rden = 1.f / den;
            const float y_in = fmaf(hk * fmaf(sk * xi, xi, dk * xo), rden, yk);
            const float num = sk * sk * (fmaf(dk1 * xi, xi, dk * om * om) + 2.f * sk * xo);
            const float ld_in = __logf(num * rden * rden);

            outg[(size_t)(row0 + srow) * 64 + 32 + gdim] = inside ? y_in : x;
            ldacc += inside ? ld_in : 0.f;
        }
        __syncthreads();
        xcur = xnext;
    }

    // ---- logdet: reduce over the 4 lanes (dim groups) sharing each row ----
    {
        float v = ldacc;
        v += __shfl_xor(v, 1);
        v += __shfl_xor(v, 2);
        if (dim == 0)
            outg[(size_t)nrows * 64 + row0 + srow] = v;
    }
}

extern "C" void kernel_launch(void* const* d_in, const int* in_sizes, int n_in,
                              void* d_out, int out_size, void* d_ws, size_t ws_size,
                              hipStream_t stream) {
    const float* x  = (const float*)d_in[0];
    const float* W1 = (const float*)d_in[1];
    const float* b1 = (const float*)d_in[2];
    const float* W2 = (const float*)d_in[3];
    const float* b2 = (const float*)d_in[4];
    const float* W3 = (const float*)d_in[5];
    const float* b3 = (const float*)d_in[6];
    const float* W4 = (const float*)d_in[7];
    const float* b4 = (const float*)d_in[8];
    float* out = (float*)d_out;
    __hip_bfloat16* ws = (__hip_bfloat16*)d_ws;

    const int nrows = in_sizes[0] / 64;   // 262144
    const int grid  = nrows / TM;         // 4096
    const bool use_ws = ws_size >= (size_t)NWELEM * 2;

    if (use_ws) {
        prep_weights<<<(NWELEM / 4 + 255) / 256, 256, 0, stream>>>(W1, W2, W3, W4, ws);
        rqs_fused_kernel<true><<<grid, 256, 0, stream>>>(x, W1, b1, W2, b2, W3, b3, W4, b4,
                                                         ws, out, nrows);
    } else {
        rqs_fused_kernel<false><<<grid, 256, 0, stream>>>(x, W1, b1, W2, b2, W3, b3, W4, b4,
                                                          ws, out, nrows);
    }
}

// Round 7
// 292.248 us; speedup vs baseline: 2.2079x; 2.2079x over previous
//
#include <hip/hip_runtime.h>
#include <hip/hip_bf16.h>

typedef __attribute__((ext_vector_type(8))) __bf16 bf16x8;
typedef __attribute__((ext_vector_type(4))) __bf16 bf16x4;
typedef __attribute__((ext_vector_type(4))) float f32x4;
typedef unsigned int u32;

#define TM 64          // rows per block (R4 lesson: do not shrink)
#define LDXM 40        // masked-x tile stride (elements)
#define LDH 136        // h tile stride (elements)
#define LDP 104        // params stride: 4 dims * 26 elems
#define MIN_BIN 1e-4f
#define MIN_SLOPE 1e-4f

// bf16 weight cache layout in d_ws (element offsets)
#define OW1 0
#define OW2 4096
#define OW3 20480
#define OW4 36864
#define NWELEM 139264   // total weight elements (W1+W2+W3+W4)

// ---- prep: fp32 weights -> bf16 cache in workspace (runs every launch) ----
__global__ void prep_weights(const float* __restrict__ W1, const float* __restrict__ W2,
                             const float* __restrict__ W3, const float* __restrict__ W4,
                             __hip_bfloat16* __restrict__ ws) {
    int e = (blockIdx.x * blockDim.x + threadIdx.x) * 4;
    if (e >= NWELEM) return;
    const float* src;
    if (e < OW2)      src = W1 + e;
    else if (e < OW3) src = W2 + (e - OW2);
    else if (e < OW4) src = W3 + (e - OW3);
    else              src = W4 + (e - OW4);
    f32x4 v = *(const f32x4*)src;
    bf16x4 o;
    o[0] = (__bf16)v[0]; o[1] = (__bf16)v[1]; o[2] = (__bf16)v[2]; o[3] = (__bf16)v[3];
    *(bf16x4*)&ws[e] = o;
}

// load 8 contiguous fp32, convert to bf16x8 (fallback path)
__device__ inline bf16x8 cvt8(const float* __restrict__ p) {
    f32x4 a = *(const f32x4*)p;
    f32x4 b = *(const f32x4*)(p + 4);
    bf16x8 r;
    r[0] = (__bf16)a[0]; r[1] = (__bf16)a[1]; r[2] = (__bf16)a[2]; r[3] = (__bf16)a[3];
    r[4] = (__bf16)b[0]; r[5] = (__bf16)b[1]; r[6] = (__bf16)b[2]; r[7] = (__bf16)b[3];
    return r;
}

template<bool USE_WS>
__device__ inline bf16x8 wfrag(const __hip_bfloat16* __restrict__ wsW,
                               const float* __restrict__ Wg, size_t off) {
    if constexpr (USE_WS) return *(const bf16x8*)(wsW + off);
    else                  return cvt8(Wg + off);
}

// ---- one dense layer: hout = relu(hin @ W^T + b), N=128, MFMA 16x16x32 ----
// A wave's TWO col-tiles (wave, wave+4) share identical A-fragments; load af
// once per mt and feed both tiles (halves ds_read_b128: 32 -> 16 per wave).
// af lifetime = inside the mt iteration only (R6 lesson: no long-lived frags).
// SWAPPED operand order mfma(W, h): lane owns 4 consecutive out cols of one
// row -> bias preloads as f32x4, store is one packed ds_write_b64 per tile.
template<bool USE_WS, int K, int LDIN>
__device__ inline void dense_layer(const __hip_bfloat16* __restrict__ wsW,
                                   const float* __restrict__ Wg,
                                   const float* __restrict__ bg,
                                   const __hip_bfloat16* hin,
                                   __hip_bfloat16* hout,
                                   int wave, int m, int q)
{
    const int n0A = wave * 16;
    const int n0B = n0A + 64;
    bf16x8 bfA[K / 32], bfB[K / 32];
#pragma unroll
    for (int kt = 0; kt < K / 32; kt++) {
        bfA[kt] = wfrag<USE_WS>(wsW, Wg, (size_t)(n0A + m) * K + kt * 32 + q * 8);
        bfB[kt] = wfrag<USE_WS>(wsW, Wg, (size_t)(n0B + m) * K + kt * 32 + q * 8);
    }
    const f32x4 biasA = *(const f32x4*)&bg[n0A + q * 4];
    const f32x4 biasB = *(const f32x4*)&bg[n0B + q * 4];
#pragma unroll
    for (int mt = 0; mt < 4; mt++) {
        const int row = mt * 16 + m;
        bf16x8 af[K / 32];
#pragma unroll
        for (int kt = 0; kt < K / 32; kt++)
            af[kt] = *(const bf16x8*)&hin[row * LDIN + kt * 32 + q * 8];
        f32x4 aA = biasA, aB = biasB;
#pragma unroll
        for (int kt = 0; kt < K / 32; kt++) {
            aA = __builtin_amdgcn_mfma_f32_16x16x32_bf16(bfA[kt], af[kt], aA, 0, 0, 0);
            aB = __builtin_amdgcn_mfma_f32_16x16x32_bf16(bfB[kt], af[kt], aB, 0, 0, 0);
        }
        bf16x4 oA, oB;
#pragma unroll
        for (int r = 0; r < 4; r++) {
            oA[r] = (__bf16)fmaxf(aA[r], 0.f);
            oB[r] = (__bf16)fmaxf(aB[r], 0.f);
        }
        *(bf16x4*)&hout[row * LDH + n0A + q * 4] = oA;
        *(bf16x4*)&hout[row * LDH + n0B + q * 4] = oB;
    }
}

// ---- layer-4 pair: both of a wave's tiles in one pass, shared A-frags
// (halves L4 ds_reads: 32 -> 16 per wave per chunk).  ORIGINAL operand order
// mfma(h, W): D row = batch (q*4+r), D col = W4 col (m).  Bias folded into
// accumulator init (R3-proven numerics).  doB is wave-uniform (wave < 3). ----
template<bool USE_WS>
__device__ inline void gemm_pair(const __hip_bfloat16* __restrict__ wsW4,
                                 const float* __restrict__ W4g,
                                 const float* __restrict__ b4g,
                                 const __hip_bfloat16* shA,
                                 int ntA, int ntB, bool doB,
                                 int m, int q, f32x4 (&accA)[4], f32x4 (&accB)[4])
{
    const int colA = ntA * 16 + m;            // <= 751
    const int colB = ntB * 16 + m;            // <= 799 when doB
    bf16x8 bfA[4], bfB[4];
#pragma unroll
    for (int kt = 0; kt < 4; kt++) {
        bfA[kt] = wfrag<USE_WS>(wsW4, W4g, (size_t)colA * 128 + kt * 32 + q * 8);
        if (doB)
            bfB[kt] = wfrag<USE_WS>(wsW4, W4g, (size_t)colB * 128 + kt * 32 + q * 8);
    }
    const float biasA = b4g[colA];
    const float biasB = doB ? b4g[colB] : 0.f;
#pragma unroll
    for (int mt = 0; mt < 4; mt++) {
        bf16x8 af[4];
#pragma unroll
        for (int kt = 0; kt < 4; kt++)
            af[kt] = *(const bf16x8*)&shA[(mt * 16 + m) * LDH + kt * 32 + q * 8];
        f32x4 aA = {biasA, biasA, biasA, biasA};
#pragma unroll
        for (int kt = 0; kt < 4; kt++)
            aA = __builtin_amdgcn_mfma_f32_16x16x32_bf16(af[kt], bfA[kt], aA, 0, 0, 0);
        accA[mt] = aA;
        if (doB) {
            f32x4 aB = {biasB, biasB, biasB, biasB};
#pragma unroll
            for (int kt = 0; kt < 4; kt++)
                aB = __builtin_amdgcn_mfma_f32_16x16x32_bf16(af[kt], bfB[kt], aB, 0, 0, 0);
            accB[mt] = aB;
        }
    }
}

// ---- param store (bias already folded into acc) ----
__device__ inline void store_tile(__hip_bfloat16* sp, int c, int nt, int m, int q,
                                  const f32x4 (&acc)[4])
{
    const int lc = nt * 16 + m - 100 * c;     // col within chunk
    if (lc < 0 || lc >= 100) return;
    const int dl = lc / 25;
    const int spcol = dl * 26 + (lc - dl * 25);
#pragma unroll
    for (int mt = 0; mt < 4; mt++)
#pragma unroll
        for (int r = 0; r < 4; r++)
            sp[(mt * 16 + q * 4 + r) * LDP + spcol] = __float2bfloat16(acc[mt][r]);
}

template<bool USE_WS>
__global__ __launch_bounds__(256, 4)
void rqs_fused_kernel(const float* __restrict__ xg,
                      const float* __restrict__ W1g, const float* __restrict__ b1g,
                      const float* __restrict__ W2g, const float* __restrict__ b2g,
                      const float* __restrict__ W3g, const float* __restrict__ b3g,
                      const float* __restrict__ W4g, const float* __restrict__ b4g,
                      const __hip_bfloat16* __restrict__ ws,
                      float* __restrict__ outg, int nrows)
{
    // LDS 34 KB -> 4 blocks/CU.  Region B time-shared: sx -> shB (h2) -> sp.
    __shared__ __align__(16) unsigned char smem[17408 + 17408];
    __hip_bfloat16* const shA = (__hip_bfloat16*)smem;              // h1/h3 [64][136]
    __hip_bfloat16* const shB = (__hip_bfloat16*)(smem + 17408);    // h2 [64][136]
    __hip_bfloat16* const sx  = (__hip_bfloat16*)(smem + 17408);    // x_masked [64][40]
    __hip_bfloat16* const sp  = (__hip_bfloat16*)(smem + 17408);    // params [64][104]

    const int tid  = threadIdx.x;
    const int wave = tid >> 6;
    const int lane = tid & 63;
    const int m    = lane & 15;
    const int q    = lane >> 4;
    const int row0 = blockIdx.x * TM;

    // ---- stage masked x (fp32->bf16) + exact fp32 passthrough y[:, :32] ----
    {
        const int r = tid >> 2, q8 = tid & 3;                 // 64 rows x 4 chunks of 8
        const float* src = &xg[(size_t)(row0 + r) * 64 + q8 * 8];
        f32x4 a = *(const f32x4*)src;
        f32x4 b = *(const f32x4*)(src + 4);
        float* dst = &outg[(size_t)(row0 + r) * 64 + q8 * 8];
        *(f32x4*)dst = a;
        *(f32x4*)(dst + 4) = b;
        bf16x8 v;
        v[0] = (__bf16)a[0]; v[1] = (__bf16)a[1]; v[2] = (__bf16)a[2]; v[3] = (__bf16)a[3];
        v[4] = (__bf16)b[0]; v[5] = (__bf16)b[1]; v[6] = (__bf16)b[2]; v[7] = (__bf16)b[3];
        *(bf16x8*)&sx[r * LDXM + q8 * 8] = v;
    }
    __syncthreads();

    // ---- MLP layers 1..3 ----
    dense_layer<USE_WS, 32, LDXM>(ws + OW1, W1g, b1g, sx, shA, wave, m, q);
    __syncthreads();
    dense_layer<USE_WS, 128, LDH>(ws + OW2, W2g, b2g, shA, shB, wave, m, q);
    __syncthreads();
    dense_layer<USE_WS, 128, LDH>(ws + OW3, W3g, b3g, shB, shA, wave, m, q);
    __syncthreads();
    // h3 persists in shA across all chunks; shB/sx dead -> sp overlays

    const int dim  = tid & 3;                 // spline: (row, 4-dim lane group)
    const int srow = tid >> 2;                // 0..63
    float ldacc = 0.f;

    // ---- pipelined layer 4 + spline, 8 chunks of 4 transform-dims ----
    // gemm_pair(c+1) -> registers runs between the barriers alongside
    // spline(c): no data dependence, MFMA/ds_read latency hides under VALU.
    f32x4 accA[4], accB[4];                   // static names, no dyn idx
    gemm_pair<USE_WS>(ws + OW4, W4g, b4g, shA, wave, wave + 4, wave < 3, m, q, accA, accB);
    float xcur = xg[(size_t)(row0 + srow) * 64 + 32 + dim];   // chunk-0 spline input

    for (int c = 0; c < 8; c++) {
        const int t0 = (25 * c) >> 2;                 // 0,6,12,18,25,31,37,43
        store_tile(sp, c, t0 + wave, m, q, accA);
        if (wave < 3) store_tile(sp, c, t0 + wave + 4, m, q, accB);
        __syncthreads();

        // issue next chunk's x load a full phase ahead of use
        const int cn = (c < 7) ? c + 1 : 7;
        const float xnext = xg[(size_t)(row0 + srow) * 64 + 32 + cn * 4 + dim];

        if (c < 7) {                                  // GEMM for chunk c+1 (reads shA only)
            const int t0n = (25 * (c + 1)) >> 2;
            gemm_pair<USE_WS>(ws + OW4, W4g, b4g, shA, t0n + wave, t0n + wave + 4,
                              wave < 3, m, q, accA, accB);
        }

        // ---- spline: one (row, dim) cell per thread (reads sp of chunk c) ----
        {
            const __hip_bfloat16* pr = &sp[srow * LDP + dim * 26];
            float raw[25];
            const u32* pu = (const u32*)pr;           // dword idx = 13*lane + j
#pragma unroll
            for (int j = 0; j < 12; j++) {
                u32 u = pu[j];
                raw[2 * j]     = __uint_as_float(u << 16);
                raw[2 * j + 1] = __uint_as_float(u & 0xffff0000u);
            }
            raw[24] = __bfloat162float(pr[24]);

            // softmax without max-subtraction: |raw| << 88, exp cannot overflow,
            // ratio is mathematically identical
            float ew[8], eh[8];
            float sumw = 0.f, sumh = 0.f;
#pragma unroll
            for (int j = 0; j < 8; j++) {
                ew[j] = __expf(raw[j]);      sumw += ew[j];
                eh[j] = __expf(raw[8 + j]);  sumh += eh[j];
            }
            const float scw = (10.f - 8.f * MIN_BIN) / sumw;
            const float sch = (10.f - 8.f * MIN_BIN) / sumh;

            const int gdim = c * 4 + dim;
            const float x = xcur;
            const bool inside = (x >= -5.f) && (x <= 5.f);
            const float xc = fminf(fmaxf(x, -5.f), 5.f);

            // sequential cumsum + bin select (matches jnp.cumsum order)
            float cx = -5.f, cy = -5.f;
            float xk = -5.f, yk = -5.f, wk = 0.f, hk = 0.f, r0 = 0.f, r1 = 0.f;
#pragma unroll
            for (int j = 0; j < 8; j++) {
                const float wj = fmaf(ew[j], scw, MIN_BIN);
                const float hj = fmaf(eh[j], sch, MIN_BIN);
                const bool sel = xc >= cx;
                xk = sel ? cx : xk;  yk = sel ? cy : yk;
                wk = sel ? wj : wk;  hk = sel ? hj : hk;
                r0 = sel ? raw[16 + j] : r0;
                r1 = sel ? raw[17 + j] : r1;
                cx += wj; cy += hj;
            }

            // softplus on the two selected slopes; __logf(1+t) replaces libm
            // log1pf (abs err ~6e-8, far below bf16 noise)
            const float dk  = MIN_SLOPE + fmaxf(r0, 0.f) + __logf(1.f + __expf(-fabsf(r0)));
            const float dk1 = MIN_SLOPE + fmaxf(r1, 0.f) + __logf(1.f + __expf(-fabsf(r1)));

            const float rw = 1.f / wk;
            const float xi = (xc - xk) * rw;
            const float om = 1.f - xi;
            const float sk = hk * rw;
            const float xo = xi * om;
            const float den = fmaf(dk1 + dk - 2.f * sk, xo, sk);
            const float rden = 1.f / den;
            const float y_in = fmaf(hk * fmaf(sk * xi, xi, dk * xo), rden, yk);
            const float num = sk * sk * (fmaf(dk1 * xi, xi, dk * om * om) + 2.f * sk * xo);
            const float ld_in = __logf(num * rden * rden);

            outg[(size_t)(row0 + srow) * 64 + 32 + gdim] = inside ? y_in : x;
            ldacc += inside ? ld_in : 0.f;
        }
        __syncthreads();
        xcur = xnext;
    }

    // ---- logdet: reduce over the 4 lanes (dim groups) sharing each row ----
    {
        float v = ldacc;
        v += __shfl_xor(v, 1);
        v += __shfl_xor(v, 2);
        if (dim == 0)
            outg[(size_t)nrows * 64 + row0 + srow] = v;
    }
}

extern "C" void kernel_launch(void* const* d_in, const int* in_sizes, int n_in,
                              void* d_out, int out_size, void* d_ws, size_t ws_size,
                              hipStream_t stream) {
    const float* x  = (const float*)d_in[0];
    const float* W1 = (const float*)d_in[1];
    const float* b1 = (const float*)d_in[2];
    const float* W2 = (const float*)d_in[3];
    const float* b2 = (const float*)d_in[4];
    const float* W3 = (const float*)d_in[5];
    const float* b3 = (const float*)d_in[6];
    const float* W4 = (const float*)d_in[7];
    const float* b4 = (const float*)d_in[8];
    float* out = (float*)d_out;
    __hip_bfloat16* ws = (__hip_bfloat16*)d_ws;

    const int nrows = in_sizes[0] / 64;   // 262144
    const int grid  = nrows / TM;         // 4096
    const bool use_ws = ws_size >= (size_t)NWELEM * 2;

    if (use_ws) {
        prep_weights<<<(NWELEM / 4 + 255) / 256, 256, 0, stream>>>(W1, W2, W3, W4, ws);
        rqs_fused_kernel<true><<<grid, 256, 0, stream>>>(x, W1, b1, W2, b2, W3, b3, W4, b4,
                                                         ws, out, nrows);
    } else {
        rqs_fused_kernel<false><<<grid, 256, 0, stream>>>(x, W1, b1, W2, b2, W3, b3, W4, b4,
                                                          ws, out, nrows);
    }
}